// Round 6
// baseline (448.860 us; speedup 1.0000x reference)
//
#include <hip/hip_runtime.h>
#include <stdint.h>

#define B_   8
#define N_   512
#define CE_  16
#define BN_  (B_*N_)   // 4096
#define Q_   8         // i-partition partials

typedef __attribute__((ext_vector_type(8))) short bf16x8;
typedef __attribute__((ext_vector_type(4))) float f32x4;
typedef __attribute__((ext_vector_type(4))) int   i32x4;

union PackA { i32x4 i; bf16x8 h; };

typedef const __attribute__((address_space(1))) void cg_void;
typedef __attribute__((address_space(3))) void ls_void;

__device__ __forceinline__ unsigned short f2bf_rne(float f) {
  unsigned u = __float_as_uint(f);
  u += 0x7FFFu + ((u >> 16) & 1u);
  return (unsigned short)(u >> 16);
}

// ---------------- K1: row precompute (m1, m2t, base) + Wc/bc ----------------
// m2t pre-swizzled: m2t[row*64 + col*4 + c] = m2[row*64 + c*16 + col]
__global__ __launch_bounds__(256) void k1_pre(
    const float* __restrict__ x,
    const float* __restrict__ W1,  const float* __restrict__ b1,
    const float* __restrict__ W2,  const float* __restrict__ b2,
    const float* __restrict__ Wn,  const float* __restrict__ bn,
    const float* __restrict__ Wo1, const float* __restrict__ bo1,
    const float* __restrict__ Wo2, const float* __restrict__ bo2,
    float* __restrict__ m1, float* __restrict__ m2t, float* __restrict__ base,
    float* __restrict__ Wc, float* __restrict__ bc)
{
  const int tid = threadIdx.x;
  if (blockIdx.x == BN_/4) {            // tiny block: Wc = Wo2@Wn, bc = Wo2@bn
    for (int idx = tid; idx < 64*64; idx += 256) {
      const int k = idx >> 6, m = idx & 63;
      float acc = 0.f;
      for (int t = 0; t < 64; ++t) acc += Wo2[k*64 + t] * Wn[t*64 + m];
      Wc[idx] = acc;
    }
    if (tid < 64) {
      float acc = 0.f;
      for (int t = 0; t < 64; ++t) acc += Wo2[tid*64 + t] * bn[t];
      bc[tid] = acc;
    }
    return;
  }
  const int r = tid >> 6, m = tid & 63;
  const int row = blockIdx.x*4 + r;
  __shared__ float xs[4][64];
  xs[r][m] = x[(size_t)row*64 + m];
  __syncthreads();
  const float* xr = xs[r];
  float a1 = b1[m], a2 = b2[m], a3 = bo1[m] + bo2[m];
  const float* w1r = W1  + m*64;
  const float* w2r = W2  + m*64;
  const float* w3r = Wo1 + m*64;
  #pragma unroll 8
  for (int c = 0; c < 64; ++c) {
    const float xv = xr[c];
    a1 += xv * w1r[c];
    a2 += xv * w2r[c];
    a3 += xv * w3r[c];
  }
  m1[(size_t)row*64 + m]   = a1;
  m2t[(size_t)row*64 + (m & 15)*4 + (m >> 4)] = a2;   // swizzled layout
  base[(size_t)row*64 + m] = a3;
}

// ---------------- K2: async-LDS-staged edge projection + relu + masked i-reduction ----
// block = 4 waves; block <-> (b, j-tile of 16, i-eighth); wave covers 16 i's.
// MFMA f32_16x16x32_bf16, K padded 16->32 (B zero for k>=16 -> garbage-A legal).
// Latency fix (Little's law): edge stream staged via global_load_lds (async DMA,
// zero VGPR cost) into a per-wave private LDS slice, 4-stage pipeline:
//   issue group t+3 -> s_waitcnt vmcnt(12) -> ds_read stage t -> compute.
// vmcnt FIFO semantics: waiting vmcnt(12) with groups t..t+3 outstanding (16 ops)
// drains exactly group t (2 edge DMAs + adj + m2 regs). No __syncthreads in the
// loop (each wave owns its slice) -> no barrier drain. LDS staging is overlaid
// with the reduction buffer (same __shared__ object keeps ordering).
__global__ __launch_bounds__(256, 4) void k2_main(
    const float* __restrict__ edge, const float* __restrict__ adj,
    const float* __restrict__ We,   const float* __restrict__ be,
    const float* __restrict__ m1,   const float* __restrict__ m2t,
    float* __restrict__ pS, float* __restrict__ pdeg)
{
  __shared__ f32x4 smem4[4][512];     // 32 KiB: per-wave 8KB staging, reused for reduction
  __shared__ float redd[4][16];

  const int tid  = threadIdx.x;
  const int lane = tid & 63;
  const int wid  = tid >> 6;
  const int col  = lane & 15;
  const int quad = lane >> 4;

  const int blk = blockIdx.x;       // 0..2047
  const int q   = blk & 7;          // i-eighth
  const int grp = blk >> 3;         // 0..255
  const int b   = grp >> 5;
  const int j0  = (grp & 31) << 4;
  const int i0  = q*64 + wid*16;

  const i32x4 izero = {0,0,0,0};

  // B fragments = We^T per 16-col chunk; ZERO for k>=16 (makes garbage-A valid).
  bf16x8 bfr[4];
  #pragma unroll
  for (int c = 0; c < 4; ++c) {
    PackA u; u.i = izero;
    if (quad < 2) {
      const float* wr = We + (c*16 + col)*CE_ + quad*8;
      unsigned p0 = ((unsigned)f2bf_rne(wr[1]) << 16) | f2bf_rne(wr[0]);
      unsigned p1 = ((unsigned)f2bf_rne(wr[3]) << 16) | f2bf_rne(wr[2]);
      unsigned p2 = ((unsigned)f2bf_rne(wr[5]) << 16) | f2bf_rne(wr[4]);
      unsigned p3 = ((unsigned)f2bf_rne(wr[7]) << 16) | f2bf_rne(wr[6]);
      i32x4 v = {(int)p0, (int)p1, (int)p2, (int)p3};
      u.i = v;
    }
    bfr[c] = u.h;
  }

  // m1 fragment (+be), laid out to match C rows j0+quad*4+reg
  f32x4 m1f[4];
  #pragma unroll
  for (int c = 0; c < 4; ++c) {
    const float bev = be[c*16 + col];
    const float* mp1 = m1 + (size_t)(b*N_ + j0 + quad*4)*64 + c*16 + col;
    m1f[c].x = mp1[0]   + bev;
    m1f[c].y = mp1[64]  + bev;
    m1f[c].z = mp1[128] + bev;
    m1f[c].w = mp1[192] + bev;
  }

  const f32x4 fzero = {0.f, 0.f, 0.f, 0.f};
  f32x4 S[4];
  S[0] = fzero; S[1] = fzero; S[2] = fzero; S[3] = fzero;
  f32x4 deg4 = fzero;

  // streams: quads 2,3 mirror quads 0,1 on edge (finite garbage for A k>=16)
  const float* ep = edge + ((size_t)(b*N_ + i0)*N_ + (j0 + col))*CE_ + (quad & 1)*8;
  const float* ap = adj  + (size_t)(b*N_ + i0)*N_ + j0 + quad*4;
  const float* mp = m2t  + (size_t)(b*N_ + i0)*64 + col*4;
  const int STEP = N_ * CE_;

  f32x4* sbase = &smem4[wid][0];    // wave-private staging slice (wave-uniform)

  auto issue_edge = [&](int slot, const float* p) {
    // lane L's 16B lands at slice + slot*2KB (+1KB for part1) + L*16
    __builtin_amdgcn_global_load_lds((cg_void*)p,
        (ls_void*)(sbase + slot*128), 16, 0, 0);
    __builtin_amdgcn_global_load_lds((cg_void*)(p + 4),
        (ls_void*)(sbase + slot*128 + 64), 16, 0, 0);
  };

  auto compute = [&](const f32x4& ce0, const f32x4& ce1,
                     const f32x4& ca, const f32x4& cm) {
    PackA ua;
    ua.i.x = (int)__builtin_amdgcn_perm(__float_as_uint(ce0.y), __float_as_uint(ce0.x), 0x07060302u);
    ua.i.y = (int)__builtin_amdgcn_perm(__float_as_uint(ce0.w), __float_as_uint(ce0.z), 0x07060302u);
    ua.i.z = (int)__builtin_amdgcn_perm(__float_as_uint(ce1.y), __float_as_uint(ce1.x), 0x07060302u);
    ua.i.w = (int)__builtin_amdgcn_perm(__float_as_uint(ce1.w), __float_as_uint(ce1.z), 0x07060302u);
    #pragma unroll
    for (int c = 0; c < 4; ++c) {
      const float m2c = cm[c];
      f32x4 cin;
      cin.x = m1f[c].x + m2c;
      cin.y = m1f[c].y + m2c;
      cin.z = m1f[c].z + m2c;
      cin.w = m1f[c].w + m2c;
      f32x4 r = __builtin_amdgcn_mfma_f32_16x16x32_bf16(ua.h, bfr[c], cin, 0, 0, 0);
      S[c].x += ca.x * fmaxf(r.x, 0.f);
      S[c].y += ca.y * fmaxf(r.y, 0.f);
      S[c].z += ca.z * fmaxf(r.z, 0.f);
      S[c].w += ca.w * fmaxf(r.w, 0.f);
    }
    deg4.x += ca.x; deg4.y += ca.y; deg4.z += ca.z; deg4.w += ca.w;
  };

  // ---- 4-stage software pipeline over 16 i-iterations ----
  f32x4 adjR[4], m2R[4];            // static-indexed after unroll -> registers
  #pragma unroll
  for (int g = 0; g < 3; ++g) {     // prologue: groups 0..2 -> slots 0..2
    issue_edge(g, ep);
    adjR[g] = *(const f32x4*)ap;
    m2R[g]  = *(const f32x4*)mp;
    ep += STEP; ap += N_; mp += 64;
  }
  int itI = 3;                      // next group index to issue (uniform)

  #pragma unroll 1
  for (int o = 0; o < 4; ++o) {
    #pragma unroll
    for (int kk = 0; kk < 4; ++kk) {
      if (itI < 16) {               // issue group it+3 into slot (kk+3)&3
        const int slot = (kk + 3) & 3;
        issue_edge(slot, ep);
        adjR[slot] = *(const f32x4*)ap;
        m2R[slot]  = *(const f32x4*)mp;
        ep += STEP; ap += N_; mp += 64;
        ++itI;
      }
      // wait until <=12 vmem outstanding -> group t (edge DMA + adj + m2) done
      __builtin_amdgcn_s_waitcnt(0x0F7C);   // vmcnt(12), lgkm/exp no-wait
      const f32x4 e0 = sbase[kk*128 + lane];
      const f32x4 e1 = sbase[kk*128 + 64 + lane];
      compute(e0, e1, adjR[kk], m2R[kk]);
    }
  }

  // ---- block reduction (staging LDS reused; per-wave region, then barrier) ----
  // row stride 68 floats: quad stride 272 % 32 = 16 -> 2-way aliasing (free)
  float* redf  = (float*)&smem4[0][0];       // 4 x 2048 floats
  float* myred = redf + wid*2048;
  #pragma unroll
  for (int c = 0; c < 4; ++c) {
    myred[(quad*4 + 0)*68 + c*16 + col] = S[c].x;
    myred[(quad*4 + 1)*68 + c*16 + col] = S[c].y;
    myred[(quad*4 + 2)*68 + c*16 + col] = S[c].z;
    myred[(quad*4 + 3)*68 + c*16 + col] = S[c].w;
  }
  if (col == 0) {
    redd[wid][quad*4 + 0] = deg4.x;
    redd[wid][quad*4 + 1] = deg4.y;
    redd[wid][quad*4 + 2] = deg4.z;
    redd[wid][quad*4 + 3] = deg4.w;
  }
  __syncthreads();

  float* oS = pS + ((size_t)q*BN_ + b*N_ + j0)*64;
  #pragma unroll
  for (int t = 0; t < 4; ++t) {
    const int idx = t*256 + tid;
    const int row = idx >> 6, ch = idx & 63;
    oS[idx] = redf[0*2048 + row*68 + ch] + redf[1*2048 + row*68 + ch]
            + redf[2*2048 + row*68 + ch] + redf[3*2048 + row*68 + ch];
  }
  if (tid < 16) {
    pdeg[(size_t)q*BN_ + b*N_ + j0 + tid] =
      redd[0][tid] + redd[1][tid] + redd[2][tid] + redd[3][tid];
  }
}

// ---------------- K3: combine partials + fused projection ----------------
__global__ __launch_bounds__(256) void k3_out(
    const float* __restrict__ pS, const float* __restrict__ pdeg,
    const float* __restrict__ base, const float* __restrict__ Wc,
    const float* __restrict__ bc, float* __restrict__ out)
{
  const int tid = threadIdx.x;
  const int r   = tid >> 6;
  const int k   = tid & 63;
  const int row = blockIdx.x*4 + r;
  __shared__ float sm[4][64];
  float s = 0.f, dr = 0.f;
  #pragma unroll
  for (int q = 0; q < Q_; ++q) {
    s  += pS[((size_t)q*BN_ + row)*64 + k];
    dr += pdeg[(size_t)q*BN_ + row];
  }
  sm[r][k] = s;
  __syncthreads();
  float acc = base[(size_t)row*64 + k] + dr * bc[k];
  const float* wr  = Wc + k*64;
  const float* smr = sm[r];
  #pragma unroll
  for (int m = 0; m < 64; ++m) acc += smr[m] * wr[m];
  out[(size_t)row*64 + k] = acc;
}

// ---------------- launch ----------------
extern "C" void kernel_launch(void* const* d_in, const int* in_sizes, int n_in,
                              void* d_out, int out_size, void* d_ws, size_t ws_size,
                              hipStream_t stream)
{
  const float* x    = (const float*)d_in[0];
  const float* adj  = (const float*)d_in[1];
  const float* edge = (const float*)d_in[2];
  const float* W1   = (const float*)d_in[3];
  const float* b1   = (const float*)d_in[4];
  const float* W2   = (const float*)d_in[5];
  const float* b2   = (const float*)d_in[6];
  const float* We   = (const float*)d_in[7];
  const float* be   = (const float*)d_in[8];
  const float* Wn   = (const float*)d_in[9];
  const float* bn   = (const float*)d_in[10];
  const float* Wo1  = (const float*)d_in[11];
  const float* bo1  = (const float*)d_in[12];
  const float* Wo2  = (const float*)d_in[13];
  const float* bo2  = (const float*)d_in[14];
  float* out = (float*)d_out;

  char* ws = (char*)d_ws;
  float* m1   = (float*)(ws);                                  // 1 MiB
  float* m2t  = (float*)(ws + (size_t)(1u<<20));               // 1 MiB (swizzled)
  float* base = (float*)(ws + (size_t)2*(1u<<20));             // 1 MiB
  float* Wc   = (float*)(ws + (size_t)3*(1u<<20));             // 16 KiB
  float* bc   = (float*)(ws + (size_t)3*(1u<<20) + 16384);     // 256 B (padded)
  float* pdeg = (float*)(ws + (size_t)3*(1u<<20) + 17408);     // Q*BN*4 = 128 KiB
  float* pS   = (float*)(ws + (size_t)3*(1u<<20) + 17408 + 131072); // Q*BN*64*4 = 8 MiB

  k1_pre<<<BN_/4 + 1, 256, 0, stream>>>(x, W1, b1, W2, b2, Wn, bn,
                                        Wo1, bo1, Wo2, bo2,
                                        m1, m2t, base, Wc, bc);
  k2_main<<<2048, 256, 0, stream>>>(edge, adj, We, be, m1, m2t, pS, pdeg);
  k3_out<<<BN_/4, 256, 0, stream>>>(pS, pdeg, base, Wc, bc, out);
}

// Round 7
// 368.367 us; speedup vs baseline: 1.2185x; 1.2185x over previous
//
#include <hip/hip_runtime.h>
#include <stdint.h>

#define B_   8
#define N_   512
#define CE_  16
#define BN_  (B_*N_)   // 4096
#define Q_   8         // i-partition partials

typedef __attribute__((ext_vector_type(8))) short bf16x8;
typedef __attribute__((ext_vector_type(4))) float f32x4;
typedef __attribute__((ext_vector_type(4))) int   i32x4;

union PackA { i32x4 i; bf16x8 h; };

__device__ __forceinline__ unsigned short f2bf_rne(float f) {
  unsigned u = __float_as_uint(f);
  u += 0x7FFFu + ((u >> 16) & 1u);
  return (unsigned short)(u >> 16);
}

// ---------------- K1: row precompute (m1, m2t, base) + Wc/bc ----------------
// m2t pre-swizzled: m2t[row*64 + col*4 + c] = m2[row*64 + c*16 + col]
__global__ __launch_bounds__(256) void k1_pre(
    const float* __restrict__ x,
    const float* __restrict__ W1,  const float* __restrict__ b1,
    const float* __restrict__ W2,  const float* __restrict__ b2,
    const float* __restrict__ Wn,  const float* __restrict__ bn,
    const float* __restrict__ Wo1, const float* __restrict__ bo1,
    const float* __restrict__ Wo2, const float* __restrict__ bo2,
    float* __restrict__ m1, float* __restrict__ m2t, float* __restrict__ base,
    float* __restrict__ Wc, float* __restrict__ bc)
{
  const int tid = threadIdx.x;
  if (blockIdx.x == BN_/4) {            // tiny block: Wc = Wo2@Wn, bc = Wo2@bn
    for (int idx = tid; idx < 64*64; idx += 256) {
      const int k = idx >> 6, m = idx & 63;
      float acc = 0.f;
      for (int t = 0; t < 64; ++t) acc += Wo2[k*64 + t] * Wn[t*64 + m];
      Wc[idx] = acc;
    }
    if (tid < 64) {
      float acc = 0.f;
      for (int t = 0; t < 64; ++t) acc += Wo2[tid*64 + t] * bn[t];
      bc[tid] = acc;
    }
    return;
  }
  const int r = tid >> 6, m = tid & 63;
  const int row = blockIdx.x*4 + r;
  __shared__ float xs[4][64];
  xs[r][m] = x[(size_t)row*64 + m];
  __syncthreads();
  const float* xr = xs[r];
  float a1 = b1[m], a2 = b2[m], a3 = bo1[m] + bo2[m];
  const float* w1r = W1  + m*64;
  const float* w2r = W2  + m*64;
  const float* w3r = Wo1 + m*64;
  #pragma unroll 8
  for (int c = 0; c < 64; ++c) {
    const float xv = xr[c];
    a1 += xv * w1r[c];
    a2 += xv * w2r[c];
    a3 += xv * w3r[c];
  }
  m1[(size_t)row*64 + m]   = a1;
  m2t[(size_t)row*64 + (m & 15)*4 + (m >> 4)] = a2;   // swizzled layout
  base[(size_t)row*64 + m] = a3;
}

// ---------------- K2: adj-predicated edge projection + relu + masked i-reduction ----
// r4 skeleton (known-good: unroll-2 double buffer, named vars only, no arrays
// under dynamic guards -> no scratch). New: BRANCHLESS adjacency gating.
//   - gate values adj[b,i,j0+col] prefetched depth-2/3 in named scalars, so the
//     predicated e-load address never depends on an in-flight load.
//   - masked lanes (adj==0) and the structurally-dead quads 2/3 (their A regs
//     multiply B=0) load from a permanently L1-hot dummy line (We base; finite
//     values -> A garbage finite -> no Inf*0 NaN; row gated by adj4 in fmac).
//   -> ~50% of 64-B edge lines never requested beyond L1.
__global__ __launch_bounds__(256, 5) void k2_main(
    const float* __restrict__ edge, const float* __restrict__ adj,
    const float* __restrict__ We,   const float* __restrict__ be,
    const float* __restrict__ m1,   const float* __restrict__ m2t,
    float* __restrict__ pS, float* __restrict__ pdeg)
{
  const int tid  = threadIdx.x;
  const int lane = tid & 63;
  const int wid  = tid >> 6;
  const int col  = lane & 15;
  const int quad = lane >> 4;

  const int blk = blockIdx.x;       // 0..2047
  const int q   = blk & 7;          // i-eighth
  const int grp = blk >> 3;         // 0..255
  const int b   = grp >> 5;
  const int j0  = (grp & 31) << 4;
  const int i0  = q*64 + wid*16;

  const i32x4 izero = {0,0,0,0};
  const bool  q01   = (quad < 2);
  const float* dummy = We;          // always-hot 64B line, finite values

  // B fragments = We^T per 16-col chunk; ZERO for k>=16 (makes garbage-A valid).
  bf16x8 bfr[4];
  #pragma unroll
  for (int c = 0; c < 4; ++c) {
    PackA u; u.i = izero;
    if (q01) {
      const float* wr = We + (c*16 + col)*CE_ + quad*8;
      unsigned p0 = ((unsigned)f2bf_rne(wr[1]) << 16) | f2bf_rne(wr[0]);
      unsigned p1 = ((unsigned)f2bf_rne(wr[3]) << 16) | f2bf_rne(wr[2]);
      unsigned p2 = ((unsigned)f2bf_rne(wr[5]) << 16) | f2bf_rne(wr[4]);
      unsigned p3 = ((unsigned)f2bf_rne(wr[7]) << 16) | f2bf_rne(wr[6]);
      i32x4 v = {(int)p0, (int)p1, (int)p2, (int)p3};
      u.i = v;
    }
    bfr[c] = u.h;
  }

  // m1 fragment (+be), laid out to match C rows j0+quad*4+reg
  f32x4 m1f[4];
  #pragma unroll
  for (int c = 0; c < 4; ++c) {
    const float bev = be[c*16 + col];
    const float* mp1 = m1 + (size_t)(b*N_ + j0 + quad*4)*64 + c*16 + col;
    m1f[c].x = mp1[0]   + bev;
    m1f[c].y = mp1[64]  + bev;
    m1f[c].z = mp1[128] + bev;
    m1f[c].w = mp1[192] + bev;
  }

  const f32x4 fzero = {0.f, 0.f, 0.f, 0.f};
  f32x4 S[4];
  S[0] = fzero; S[1] = fzero; S[2] = fzero; S[3] = fzero;
  f32x4 deg4 = fzero;

  const float* ep  = edge + ((size_t)(b*N_ + i0)*N_ + (j0 + col))*CE_ + (quad & 1)*8;
  const float* ap  = adj  + (size_t)(b*N_ + i0)*N_ + j0 + quad*4;
  const float* mp  = m2t  + (size_t)(b*N_ + i0)*64 + col*4;
  const float* apc0 = adj + (size_t)(b*N_ + i0)*N_ + j0 + col;   // gate stream
  const float* apc  = apc0;
  const int STEP = N_ * CE_;

  // gate prefetch: ac1 = gate(t+1), ac2 = gate(t+2) entering each body
  const float ac0 = apc[0];
  float ac1 = apc[N_];
  float ac2 = apc[2*N_];
  apc += 3*N_;                      // next gate load -> t=3

  // a-set for t=0 (predicated by ac0)
  const float* pe = (q01 && ac0 != 0.f) ? ep : dummy;
  f32x4 e0a  = *(const f32x4*)(pe);
  f32x4 e1a  = *(const f32x4*)(pe + 4);
  f32x4 ada  = *(const f32x4*)(ap);
  f32x4 ma4  = *(const f32x4*)(mp);
  f32x4 e0b, e1b, adb, mb4;

  auto compute = [&](const f32x4& ce0, const f32x4& ce1,
                     const f32x4& ca, const f32x4& cm) {
    PackA ua;
    ua.i.x = (int)__builtin_amdgcn_perm(__float_as_uint(ce0.y), __float_as_uint(ce0.x), 0x07060302u);
    ua.i.y = (int)__builtin_amdgcn_perm(__float_as_uint(ce0.w), __float_as_uint(ce0.z), 0x07060302u);
    ua.i.z = (int)__builtin_amdgcn_perm(__float_as_uint(ce1.y), __float_as_uint(ce1.x), 0x07060302u);
    ua.i.w = (int)__builtin_amdgcn_perm(__float_as_uint(ce1.w), __float_as_uint(ce1.z), 0x07060302u);
    #pragma unroll
    for (int c = 0; c < 4; ++c) {
      const float m2c = cm[c];
      f32x4 cin;
      cin.x = m1f[c].x + m2c;
      cin.y = m1f[c].y + m2c;
      cin.z = m1f[c].z + m2c;
      cin.w = m1f[c].w + m2c;
      f32x4 r = __builtin_amdgcn_mfma_f32_16x16x32_bf16(ua.h, bfr[c], cin, 0, 0, 0);
      S[c].x += ca.x * fmaxf(r.x, 0.f);
      S[c].y += ca.y * fmaxf(r.y, 0.f);
      S[c].z += ca.z * fmaxf(r.z, 0.f);
      S[c].w += ca.w * fmaxf(r.w, 0.f);
    }
    deg4.x += ca.x; deg4.y += ca.y; deg4.z += ca.z; deg4.w += ca.w;
  };

  #pragma unroll 1
  for (int it = 0; it < 16; it += 2) {
    // ---- first half: load t+1 (b-set, predicated by ac1), gate t+3 ----
    ep += STEP; ap += N_; mp += 64;
    pe  = (q01 && ac1 != 0.f) ? ep : dummy;
    e0b = *(const f32x4*)(pe);
    e1b = *(const f32x4*)(pe + 4);
    adb = *(const f32x4*)(ap);
    mb4 = *(const f32x4*)(mp);
    const float acn0 = *((it + 3 < 16) ? apc : apc0);  // clamped gate load
    apc += N_;
    compute(e0a, e1a, ada, ma4);
    // ---- second half: load t+2 (a-set, predicated by ac2), gate t+4 ----
    const int adv = (it < 14) ? 1 : 0;                 // last pair: legal re-read
    ep += adv * STEP; ap += adv * N_; mp += adv * 64;
    pe  = (q01 && ac2 != 0.f) ? ep : dummy;
    e0a = *(const f32x4*)(pe);
    e1a = *(const f32x4*)(pe + 4);
    ada = *(const f32x4*)(ap);
    ma4 = *(const f32x4*)(mp);
    const float acn1 = *((it + 4 < 16) ? apc : apc0);  // clamped gate load
    apc += N_;
    compute(e0b, e1b, adb, mb4);
    // rotate gates (scalars, named)
    ac1 = acn0; ac2 = acn1;
  }

  // block reduction across the 4 waves (same (b,jt), different i-chunks)
  // row stride 68 floats: quad stride 272 % 32 = 16 -> 2-way aliasing (free)
  __shared__ float red[4][16*68];
  __shared__ float redd[4][16];
  #pragma unroll
  for (int c = 0; c < 4; ++c) {
    red[wid][(quad*4 + 0)*68 + c*16 + col] = S[c].x;
    red[wid][(quad*4 + 1)*68 + c*16 + col] = S[c].y;
    red[wid][(quad*4 + 2)*68 + c*16 + col] = S[c].z;
    red[wid][(quad*4 + 3)*68 + c*16 + col] = S[c].w;
  }
  if (col == 0) {
    redd[wid][quad*4 + 0] = deg4.x;
    redd[wid][quad*4 + 1] = deg4.y;
    redd[wid][quad*4 + 2] = deg4.z;
    redd[wid][quad*4 + 3] = deg4.w;
  }
  __syncthreads();

  float* oS = pS + ((size_t)q*BN_ + b*N_ + j0)*64;
  #pragma unroll
  for (int t = 0; t < 4; ++t) {
    const int idx = t*256 + tid;
    const int row = idx >> 6, ch = idx & 63;
    oS[idx] = red[0][row*68 + ch] + red[1][row*68 + ch]
            + red[2][row*68 + ch] + red[3][row*68 + ch];
  }
  if (tid < 16) {
    pdeg[(size_t)q*BN_ + b*N_ + j0 + tid] =
      redd[0][tid] + redd[1][tid] + redd[2][tid] + redd[3][tid];
  }
}

// ---------------- K3: combine partials + fused projection ----------------
__global__ __launch_bounds__(256) void k3_out(
    const float* __restrict__ pS, const float* __restrict__ pdeg,
    const float* __restrict__ base, const float* __restrict__ Wc,
    const float* __restrict__ bc, float* __restrict__ out)
{
  const int tid = threadIdx.x;
  const int r   = tid >> 6;
  const int k   = tid & 63;
  const int row = blockIdx.x*4 + r;
  __shared__ float sm[4][64];
  float s = 0.f, dr = 0.f;
  #pragma unroll
  for (int q = 0; q < Q_; ++q) {
    s  += pS[((size_t)q*BN_ + row)*64 + k];
    dr += pdeg[(size_t)q*BN_ + row];
  }
  sm[r][k] = s;
  __syncthreads();
  float acc = base[(size_t)row*64 + k] + dr * bc[k];
  const float* wr  = Wc + k*64;
  const float* smr = sm[r];
  #pragma unroll
  for (int m = 0; m < 64; ++m) acc += smr[m] * wr[m];
  out[(size_t)row*64 + k] = acc;
}

// ---------------- launch ----------------
extern "C" void kernel_launch(void* const* d_in, const int* in_sizes, int n_in,
                              void* d_out, int out_size, void* d_ws, size_t ws_size,
                              hipStream_t stream)
{
  const float* x    = (const float*)d_in[0];
  const float* adj  = (const float*)d_in[1];
  const float* edge = (const float*)d_in[2];
  const float* W1   = (const float*)d_in[3];
  const float* b1   = (const float*)d_in[4];
  const float* W2   = (const float*)d_in[5];
  const float* b2   = (const float*)d_in[6];
  const float* We   = (const float*)d_in[7];
  const float* be   = (const float*)d_in[8];
  const float* Wn   = (const float*)d_in[9];
  const float* bn   = (const float*)d_in[10];
  const float* Wo1  = (const float*)d_in[11];
  const float* bo1  = (const float*)d_in[12];
  const float* Wo2  = (const float*)d_in[13];
  const float* bo2  = (const float*)d_in[14];
  float* out = (float*)d_out;

  char* ws = (char*)d_ws;
  float* m1   = (float*)(ws);                                  // 1 MiB
  float* m2t  = (float*)(ws + (size_t)(1u<<20));               // 1 MiB (swizzled)
  float* base = (float*)(ws + (size_t)2*(1u<<20));             // 1 MiB
  float* Wc   = (float*)(ws + (size_t)3*(1u<<20));             // 16 KiB
  float* bc   = (float*)(ws + (size_t)3*(1u<<20) + 16384);     // 256 B (padded)
  float* pdeg = (float*)(ws + (size_t)3*(1u<<20) + 17408);     // Q*BN*4 = 128 KiB
  float* pS   = (float*)(ws + (size_t)3*(1u<<20) + 17408 + 131072); // Q*BN*64*4 = 8 MiB

  k1_pre<<<BN_/4 + 1, 256, 0, stream>>>(x, W1, b1, W2, b2, Wn, bn,
                                        Wo1, bo1, Wo2, bo2,
                                        m1, m2t, base, Wc, bc);
  k2_main<<<2048, 256, 0, stream>>>(edge, adj, We, be, m1, m2t, pS, pdeg);
  k3_out<<<BN_/4, 256, 0, stream>>>(pS, pdeg, base, Wc, bc, out);
}